// Round 14
// baseline (1263.934 us; speedup 1.0000x reference)
//
#include <hip/hip_runtime.h>
#include <hip/hip_bf16.h>
#include <math.h>

typedef __hip_bfloat16 bf16;
typedef __attribute__((ext_vector_type(8))) short short8;
typedef __attribute__((ext_vector_type(4))) float floatx4;

#define B_    16
#define L0_   4096
#define IN_   8
#define D_    256
#define H_    8
#define DK_   32
#define FF_   1024
#define PRED_ 24
#define UMAX_ 48
#define NS_   4
#define NSV_  8
#define SCALE_ 0.17677669529663687f   // 1/sqrt(32)

__device__ __forceinline__ float b2f(bf16 v) { return __bfloat162float(v); }
__device__ __forceinline__ bf16  f2b(float v){ return __float2bfloat16(v); }
__device__ __forceinline__ short f2s(float v){ bf16 x = f2b(v); return *(short*)&x; }
__device__ __forceinline__ float gelu_exact(float x){
  return 0.5f * x * (1.0f + erff(x * 0.7071067811865476f));
}
__device__ __forceinline__ float eluf(float x){ return x > 0.f ? x : (expf(x) - 1.f); }
__device__ __forceinline__ float ldf(const void* p, size_t i, int f){
  return f ? ((const float*)p)[i] : b2f(((const bf16*)p)[i]);
}
__device__ __forceinline__ void gld16(const void* g, const short* l){
  __builtin_amdgcn_global_load_lds(
      (const __attribute__((address_space(1))) unsigned int*)g,
      (__attribute__((address_space(3))) unsigned int*)l, 16, 0, 0);
}
__device__ __forceinline__ void unpack8(uint4 v, float* o){
  o[0] = __uint_as_float(v.x << 16); o[1] = __uint_as_float(v.x & 0xffff0000u);
  o[2] = __uint_as_float(v.y << 16); o[3] = __uint_as_float(v.y & 0xffff0000u);
  o[4] = __uint_as_float(v.z << 16); o[5] = __uint_as_float(v.z & 0xffff0000u);
  o[6] = __uint_as_float(v.w << 16); o[7] = __uint_as_float(v.w & 0xffff0000u);
}
__device__ __forceinline__ void unpack4(uint2 v, float* o){
  o[0] = __uint_as_float(v.x << 16); o[1] = __uint_as_float(v.x & 0xffff0000u);
  o[2] = __uint_as_float(v.y << 16); o[3] = __uint_as_float(v.y & 0xffff0000u);
}
__device__ __forceinline__ unsigned pack2(float a, float b){
  bf16 x = f2b(a), y = f2b(b);
  return (unsigned)*(unsigned short*)&x | ((unsigned)*(unsigned short*)&y << 16);
}
__device__ __forceinline__ void ld_row32(const bf16* p, float* o){
  const uint4* q = (const uint4*)p;
  uint4 a = q[0], b = q[1], c = q[2], d = q[3];
  unpack8(a, o); unpack8(b, o + 8); unpack8(c, o + 16); unpack8(d, o + 24);
}

// ---------------- dtype detector (+ zero scratch init) ----------------
__global__ __launch_bounds__(256) void detect_mode_kernel(
    const unsigned short* __restrict__ x16, int* __restrict__ flag,
    bf16* __restrict__ zbuf)
{
  int tid = threadIdx.x;
  if (tid < 32) zbuf[tid] = f2b(0.f);
  int cnt = 0;
  for (int i = tid; i < 512; i += 256) {
    unsigned short v = x16[2 * i];
    int expo = (v >> 7) & 0xFF;
    if (expo >= 0x90) cnt++;
  }
  __shared__ int red[256];
  red[tid] = cnt;
  __syncthreads();
  for (int s = 128; s > 0; s >>= 1) {
    if (tid < s) red[tid] += red[tid + s];
    __syncthreads();
  }
  if (tid == 0) flag[0] = (red[0] > 8) ? 1 : 0;
}

// ---------------- canonicalize one array to bf16 ----------------
__global__ __launch_bounds__(256) void canon_kernel(
    const void* __restrict__ src, bf16* __restrict__ dst, int n,
    const int* __restrict__ flag)
{
  int i = blockIdx.x * 256 + threadIdx.x;
  if (i >= n) return;
  dst[i] = f2b(ldf(src, i, flag[0]));
}

// ---------------- transpose weight [K][N] -> [N][K], per layer ----------------
__global__ __launch_bounds__(256) void transpose_w_kernel(
    const void* __restrict__ src, bf16* __restrict__ dst, int K, int N,
    const int* __restrict__ flag, int lstride)
{
  int i = blockIdx.x * 256 + threadIdx.x;
  if (i >= K * N) return;
  size_t soff = (size_t)blockIdx.y * K * N;
  int k = i / N, n = i % N;
  dst[(size_t)blockIdx.y * lstride + (size_t)n * K + k] = f2b(ldf(src, soff + i, flag[0]));
}

// ---------------- conv weight [o][c][3] -> [t][o][c], per layer ----------------
__global__ __launch_bounds__(256) void transpose_cw_kernel(
    const void* __restrict__ src, bf16* __restrict__ dst,
    const int* __restrict__ flag)
{
  int i = blockIdx.x * 256 + threadIdx.x;
  if (i >= D_ * D_ * 3) return;
  size_t off = (size_t)blockIdx.y * D_ * D_ * 3;
  int o = i / (D_ * 3), c = (i / 3) % D_, t = i % 3;
  dst[off + ((size_t)t * D_ + o) * D_ + c] = f2b(ldf(src, off + i, flag[0]));
}

// ---------------- embed: 8 tokens per block ----------------
__global__ __launch_bounds__(256) void embed_kernel(
    const void* __restrict__ x, const void* __restrict__ in_w,
    const void* __restrict__ in_b, const void* __restrict__ pos,
    const int* __restrict__ flag, bf16* __restrict__ h)
{
  int d = threadIdx.x;
  int f = flag[0];
  float wcol[IN_];
#pragma unroll
  for (int k = 0; k < IN_; ++k) wcol[k] = ldf(in_w, k * D_ + d, f);
  float bd = ldf(in_b, d, f);
  int t0 = blockIdx.x * 8;
#pragma unroll
  for (int t = 0; t < 8; ++t) {
    int token = t0 + t;
    int l = token & (L0_ - 1);
    float s = bd + ldf(pos, (size_t)l * D_ + d, f);
#pragma unroll
    for (int k = 0; k < IN_; ++k)
      s += ldf(x, (size_t)token * IN_ + k, f) * wcol[k];
    h[(size_t)token * D_ + d] = f2b(s);
  }
}

// ---------------- MFMA GEMM (BK=64, XCD swizzle, LDS-transposed epilogue) ----
// grid = cn * rm (1-D). c = (id>>3)%cn, r = (id&7) + 8*((id>>3)/cn).
// HM=0: C token-major [M][N], bias=b0. HM=1: merged QKV head-major; N=768.
template<int ACT, int HM>
__global__ __launch_bounds__(256) void mfma_gemm(
    const bf16* __restrict__ A, const bf16* __restrict__ Wt,
    const bf16* __restrict__ b0, const bf16* __restrict__ b1,
    const bf16* __restrict__ b2, bf16* __restrict__ C,
    int M, int N, int K, int Lsh, size_t partStride, int cn)
{
  __shared__ short smem[2 * 128 * 64];   // staging A|B; reused as 128x128 C tile
  short* As = smem;
  short* Bs = smem + 128 * 64;
  int tid = threadIdx.x;
  int w = tid >> 6, lane = tid & 63;
  int ln = lane & 15, qd = lane >> 4;
  int id = blockIdx.x;
  int idx = id >> 3;
  int cblk = idx % cn;
  int rblk = (id & 7) + ((idx / cn) << 3);
  int bm = rblk << 7, bn = cblk << 7;
  int wm = (w >> 1) << 6, wn = (w & 1) << 6;

  floatx4 acc[4][4];
#pragma unroll
  for (int mi = 0; mi < 4; ++mi)
#pragma unroll
    for (int ni = 0; ni < 4; ++ni) {
      acc[mi][ni][0] = 0.f; acc[mi][ni][1] = 0.f;
      acc[mi][ni][2] = 0.f; acc[mi][ni][3] = 0.f;
    }

  int rr[4], ofs[4];
#pragma unroll
  for (int t = 0; t < 4; ++t) {
    int p = (w << 8) + (t << 6) + lane;
    int r = p >> 3;
    ofs[t] = (((p & 7) ^ (r & 7)) << 3);
    rr[t] = r;
  }
  const bf16* pA[4]; const bf16* pB[4]; short* dst[4];
#pragma unroll
  for (int t = 0; t < 4; ++t) {
    pA[t] = A + (size_t)(bm + rr[t]) * K + ofs[t];
    pB[t] = Wt + (size_t)(bn + rr[t]) * K + ofs[t];
    dst[t] = As + (((w << 2) + t) << 9);
  }

  for (int k0 = 0; k0 < K; k0 += 64) {
    __syncthreads();
#pragma unroll
    for (int t = 0; t < 4; ++t) gld16(pA[t] + k0, dst[t]);
#pragma unroll
    for (int t = 0; t < 4; ++t) gld16(pB[t] + k0, dst[t] + 128 * 64);
    __syncthreads();
#pragma unroll
    for (int kb = 0; kb < 2; ++kb) {
      short8 af[4], bff[4];
#pragma unroll
      for (int mi = 0; mi < 4; ++mi) {
        int r = wm + mi * 16 + ln;
        af[mi] = *(const short8*)(As + (r << 6) + ((((kb << 2) + qd) ^ (r & 7)) << 3));
      }
#pragma unroll
      for (int ni = 0; ni < 4; ++ni) {
        int r = wn + ni * 16 + ln;
        bff[ni] = *(const short8*)(Bs + (r << 6) + ((((kb << 2) + qd) ^ (r & 7)) << 3));
      }
#pragma unroll
      for (int mi = 0; mi < 4; ++mi)
#pragma unroll
        for (int ni = 0; ni < 4; ++ni)
          acc[mi][ni] = __builtin_amdgcn_mfma_f32_16x16x32_bf16(
              af[mi], bff[ni], acc[mi][ni], 0, 0, 0);
    }
  }

  // ---- epilogue: frags -> LDS tile (bias+act applied) -> 16B coalesced stores
  __syncthreads();
#pragma unroll
  for (int ni = 0; ni < 4; ++ni) {
    int col = bn + wn + ni * 16 + ln;
    const bf16* bsel = b0;
    int cm = col;
    if (HM) {
      int part = col >> 8;
      cm = col & 255;
      bsel = (part == 0) ? b0 : ((part == 1) ? b1 : b2);
    }
    float bv = b2f(bsel[cm]);
    int cl = wn + ni * 16 + ln;
#pragma unroll
    for (int mi = 0; mi < 4; ++mi) {
      int rowl = wm + mi * 16 + (qd << 2);
#pragma unroll
      for (int r = 0; r < 4; ++r) {
        float v = acc[mi][ni][r] + bv;
        if (ACT == 1) v = gelu_exact(v);
        int rl = rowl + r;
        smem[(rl << 7) + ((((cl >> 3) ^ (rl & 15))) << 3) + (cl & 7)] = f2s(v);
      }
    }
  }
  __syncthreads();
#pragma unroll
  for (int it = 0; it < 8; ++it) {
    int idx2 = it * 256 + tid;
    int rl = idx2 >> 4, c = idx2 & 15;
    uint4 v = *(const uint4*)(smem + (rl << 7) + ((c ^ (rl & 15)) << 3));
    int row = bm + rl;
    int colbase = bn + (c << 3);
    if (HM) {
      int part = colbase >> 8;
      int cmb = colbase & 255;
      int hh = cmb >> 5, dk = cmb & 31;
      int bb = row >> Lsh, ll = row & ((1 << Lsh) - 1);
      *(uint4*)(C + part * partStride +
                ((((size_t)(bb * H_ + hh)) << Lsh) + ll) * 32 + dk) = v;
    } else {
      *(uint4*)(C + (size_t)row * N + colbase) = v;
    }
  }
}

// ---------------- MFMA fused conv3(pad1)+bias+ELU+maxpool2 (BK=32) ----------------
__global__ __launch_bounds__(256) void mfma_conv_distill(
    const bf16* __restrict__ hsrc, const bf16* __restrict__ WtC,
    const bf16* __restrict__ cb, bf16* __restrict__ outp,
    const bf16* __restrict__ zbuf, int L)
{
  __shared__ short As[128 * 32];
  __shared__ short Bs[128 * 32];
  int tid = threadIdx.x;
  int w = tid >> 6, lane = tid & 63;
  int ln = lane & 15, qd = lane >> 4;
  int id = blockIdx.x;
  int idx = id >> 3;
  int cblk = idx & 1;
  int rblk = (id & 7) + ((idx >> 1) << 3);
  int bn = cblk << 7;
  int bpb = L >> 7;
  int b = rblk / bpb;
  int p0 = (rblk % bpb) << 7;
  int wm = (w >> 1) << 6, wn = (w & 1) << 6;

  floatx4 acc[4][4];
#pragma unroll
  for (int mi = 0; mi < 4; ++mi)
#pragma unroll
    for (int ni = 0; ni < 4; ++ni) {
      acc[mi][ni][0] = 0.f; acc[mi][ni][1] = 0.f;
      acc[mi][ni][2] = 0.f; acc[mi][ni][3] = 0.f;
    }

  int s0 = (w << 7) + lane, s1 = s0 + 64;
  int r0 = s0 >> 2, c0 = (s0 & 3) ^ (r0 & 3);
  int r1 = s1 >> 2, c1 = (s1 & 3) ^ (r1 & 3);
  short* ldsA = As + (w << 10);
  short* ldsB = Bs + (w << 10);

  for (int tap = 0; tap < 3; ++tap) {
    const bf16* wt = WtC + (size_t)tap * D_ * D_;
    int pos0 = p0 + r0 + tap - 1;
    int pos1 = p0 + r1 + tap - 1;
    const bf16* gA0 = (pos0 >= 0 && pos0 < L)
        ? hsrc + ((size_t)b * L + pos0) * D_ + (c0 << 3) : zbuf;
    const bf16* gA1 = (pos1 >= 0 && pos1 < L)
        ? hsrc + ((size_t)b * L + pos1) * D_ + (c1 << 3) : zbuf;
    int stepA0 = (pos0 >= 0 && pos0 < L) ? 1 : 0;
    int stepA1 = (pos1 >= 0 && pos1 < L) ? 1 : 0;
    const bf16* gB0 = wt + (size_t)(bn + r0) * D_ + (c0 << 3);
    const bf16* gB1 = wt + (size_t)(bn + r1) * D_ + (c1 << 3);
    for (int k0 = 0; k0 < D_; k0 += 32) {
      __syncthreads();
      gld16(gA0 + (size_t)k0 * stepA0, ldsA);
      gld16(gA1 + (size_t)k0 * stepA1, ldsA + 512);
      gld16(gB0 + k0, ldsB);
      gld16(gB1 + k0, ldsB + 512);
      __syncthreads();
      short8 af[4], bff[4];
#pragma unroll
      for (int mi = 0; mi < 4; ++mi) {
        int r = wm + mi * 16 + ln;
        af[mi] = *(const short8*)(As + (r << 5) + ((qd ^ (r & 3)) << 3));
      }
#pragma unroll
      for (int ni = 0; ni < 4; ++ni) {
        int r = wn + ni * 16 + ln;
        bff[ni] = *(const short8*)(Bs + (r << 5) + ((qd ^ (r & 3)) << 3));
      }
#pragma unroll
      for (int mi = 0; mi < 4; ++mi)
#pragma unroll
        for (int ni = 0; ni < 4; ++ni)
          acc[mi][ni] = __builtin_amdgcn_mfma_f32_16x16x32_bf16(
              af[mi], bff[ni], acc[mi][ni], 0, 0, 0);
    }
  }

  int Lh = L >> 1;
#pragma unroll
  for (int ni = 0; ni < 4; ++ni) {
    int col = bn + wn + ni * 16 + ln;
    float bv = b2f(cb[col]);
#pragma unroll
    for (int mi = 0; mi < 4; ++mi) {
      float y0 = eluf(acc[mi][ni][0] + bv);
      float y1 = eluf(acc[mi][ni][1] + bv);
      float y2 = eluf(acc[mi][ni][2] + bv);
      float y3 = eluf(acc[mi][ni][3] + bv);
      int prow = (p0 + wm + mi * 16 + (qd << 2)) >> 1;
      outp[((size_t)b * Lh + prow) * D_ + col]     = f2b(fmaxf(y0, y1));
      outp[((size_t)b * Lh + prow + 1) * D_ + col] = f2b(fmaxf(y2, y3));
    }
  }
}

// ---------------- ProbSparse M scores (K[idx] staged in LDS, float4 dots) ----
__global__ __launch_bounds__(256) void prob_scores_kernel(
    const bf16* __restrict__ Qh, const bf16* __restrict__ Kh,
    const int* __restrict__ idx, float* __restrict__ Mout, int L, int u)
{
  __shared__ float ks[UMAX_][32];
  int tid = threadIdx.x;
  int bpb = L >> 8;
  int bh = blockIdx.x / bpb;
  int l  = (blockIdx.x % bpb) * 256 + tid;
  if (tid < u * 4) {
    int t = tid >> 2, c = tid & 3;
    int ls = idx[t];
    if (ls < 0) ls = 0; if (ls >= L) ls = L - 1;
    uint4 v = *(const uint4*)(Kh + ((size_t)bh * L + ls) * 32 + c * 8);
    unpack8(v, &ks[t][c * 8]);
  }
  __syncthreads();
  float qv[32];
  ld_row32(Qh + ((size_t)bh * L + l) * 32, qv);
  float mx = -3.4e38f, sm = 0.f;
  for (int t = 0; t < u; ++t) {
    float s = 0.f;
#pragma unroll
    for (int j4 = 0; j4 < 8; ++j4) {
      float4 k4 = *(const float4*)&ks[t][j4 * 4];
      s += qv[4*j4+0]*k4.x + qv[4*j4+1]*k4.y + qv[4*j4+2]*k4.z + qv[4*j4+3]*k4.w;
    }
    s *= SCALE_;
    mx = fmaxf(mx, s);
    sm += s;
  }
  Mout[(size_t)bh * L + l] = mx - sm / (float)u;
}

// ---------------- top-k: radix-select (order-free set semantics) ----------
__global__ __launch_bounds__(256) void topk_kernel(
    const float* __restrict__ M, int* __restrict__ top, int L, int u)
{
  __shared__ unsigned int hist[256];
  __shared__ unsigned int prefS, kS;
  __shared__ int cntG, tieCnt;
  __shared__ int tieList[256];
  int bh = blockIdx.x;
  int tid = threadIdx.x;
  int w = tid >> 6, lane = tid & 63;
  int nper = L >> 8;

  unsigned int key[16];
  for (int i = 0; i < nper; ++i) {
    unsigned int ub = __float_as_uint(M[(size_t)bh * L + i * 256 + tid]);
    key[i] = (ub & 0x80000000u) ? ~ub : (ub | 0x80000000u);
  }

  unsigned int pref = 0, k = (unsigned int)u;
  for (int round = 0; round < 4; ++round) {
    int shift = 24 - (round << 3);
    hist[tid] = 0;
    __syncthreads();
    for (int i = 0; i < nper; ++i) {
      unsigned int kk = key[i];
      if (round == 0 || (kk >> (shift + 8)) == pref)
        atomicAdd(&hist[(kk >> shift) & 0xFFu], 1u);
    }
    __syncthreads();
    if (w == 0) {
      int d0 = lane << 2;
      unsigned int h0 = hist[d0], h1 = hist[d0 + 1];
      unsigned int h2 = hist[d0 + 2], h3 = hist[d0 + 3];
      unsigned int lsum = h0 + h1 + h2 + h3;
      unsigned int incl = lsum;
#pragma unroll
      for (int off = 1; off < 64; off <<= 1) {
        unsigned int o = __shfl_down(incl, off);
        if (lane + off < 64) incl += o;
      }
      unsigned int e3 = incl - lsum;
      unsigned int e2 = e3 + h3;
      unsigned int e1 = e2 + h2;
      unsigned int e0 = e1 + h1;
      if (e3 < k && k <= e3 + h3) { prefS = (pref << 8) | (d0 + 3); kS = k - e3; }
      if (e2 < k && k <= e2 + h2) { prefS = (pref << 8) | (d0 + 2); kS = k - e2; }
      if (e1 < k && k <= e1 + h1) { prefS = (pref << 8) | (d0 + 1); kS = k - e1; }
      if (e0 < k && k <= e0 + h0) { prefS = (pref << 8) | (d0 + 0); kS = k - e0; }
    }
    __syncthreads();
    pref = prefS;
    k = kS;
    __syncthreads();
  }

  unsigned int T = pref;
  if (tid == 0) { cntG = 0; tieCnt = 0; }
  __syncthreads();
  for (int i = 0; i < nper; ++i) {
    unsigned int kk = key[i];
    int lidx = i * 256 + tid;
    if (kk > T) {
      int pos = atomicAdd(&cntG, 1);
      if (pos < u) top[bh * u + pos] = lidx;
    } else if (kk == T) {
      int tpos = atomicAdd(&tieCnt, 1);
      if (tpos < 256) tieList[tpos] = lidx;
    }
  }
  __syncthreads();
  if (tid == 0) {
    int base = cntG;
    int E = tieCnt; if (E > 256) E = 256;
    for (int t = 0; t < (int)k && base + t < u; ++t) {
      int best = 0x7fffffff, bj = -1;
      for (int j = 0; j < E; ++j) {
        int v = tieList[j];
        if (v >= 0 && v < best) { best = v; bj = j; }
      }
      if (bj >= 0) { tieList[bj] = -1; top[bh * u + base + t] = best; }
      else top[bh * u + base + t] = 0;
    }
  }
}

// ---------------- topq attention: MFMA flash, per (b,h,slice) ----------------
__global__ __launch_bounds__(256) void topq_attn_mfma(
    const bf16* __restrict__ Qh, const bf16* __restrict__ Kh,
    const bf16* __restrict__ Vh, const int* __restrict__ top,
    float* __restrict__ part_m, float* __restrict__ part_s,
    float* __restrict__ part_acc, int L, int u)
{
  __shared__ short Qs[64 * 32];
  __shared__ short Ks[128 * 32];
  __shared__ short Vs[128 * 32];
  __shared__ short Ps[4][64 * 32];
  __shared__ float mrow[64];
  __shared__ float redm[4][64];
  __shared__ float redl[4][64];

  int bh = blockIdx.x, sl = blockIdx.y;
  int tid = threadIdx.x;
  int w = tid >> 6, lane = tid & 63;
  int ln = lane & 15, qd = lane >> 4;
  int Ls = L / NS_;
  int lbase = sl * Ls;
  const bf16* Kbase = Kh + (size_t)bh * L * 32;
  const bf16* Vbase = Vh + (size_t)bh * L * 32;

  {
    int r = tid >> 2, cpos = tid & 3, corig = cpos ^ (r & 3);
    uint4 v = make_uint4(0, 0, 0, 0);
    if (r < u) {
      int lq = top[bh * u + r];
      if (lq < 0) lq = 0; if (lq >= L) lq = L - 1;
      v = *(const uint4*)(Qh + ((size_t)bh * L + lq) * 32 + corig * 8);
    }
    *(uint4*)(Qs + r * 32 + cpos * 8) = v;
  }
  __syncthreads();

  short8 aq[4];
#pragma unroll
  for (int mi = 0; mi < 4; ++mi) {
    int r = mi * 16 + ln;
    aq[mi] = *(const short8*)(Qs + (r << 5) + ((qd ^ (r & 3)) << 3));
  }

  int s0 = (w << 7) + lane, s1 = s0 + 64;
  int r0 = s0 >> 2, c0 = (s0 & 3) ^ (r0 & 3);
  int r1 = s1 >> 2, c1 = (s1 & 3) ^ (r1 & 3);
  short* ldsK = Ks + (w << 10);
  short* ldsV = Vs + (w << 10);
  int nch = Ls >> 7;

  float m_run[16];
#pragma unroll
  for (int i = 0; i < 16; ++i) m_run[i] = -3.4e38f;

  for (int ch = 0; ch < nch; ++ch) {
    int tok0 = lbase + (ch << 7);
    __syncthreads();
    gld16(Kbase + (size_t)(tok0 + r0) * 32 + (c0 << 3), ldsK);
    gld16(Kbase + (size_t)(tok0 + r1) * 32 + (c1 << 3), ldsK + 512);
    __syncthreads();
    short8 bk[2];
#pragma unroll
    for (int ni = 0; ni < 2; ++ni) {
      int r = (w << 5) + ni * 16 + ln;
      bk[ni] = *(const short8*)(Ks + (r << 5) + ((qd ^ (r & 3)) << 3));
    }
#pragma unroll
    for (int mi = 0; mi < 4; ++mi)
#pragma unroll
      for (int ni = 0; ni < 2; ++ni) {
        floatx4 s = {0.f, 0.f, 0.f, 0.f};
        s = __builtin_amdgcn_mfma_f32_16x16x32_bf16(aq[mi], bk[ni], s, 0, 0, 0);
#pragma unroll
        for (int r = 0; r < 4; ++r)
          m_run[mi * 4 + r] = fmaxf(m_run[mi * 4 + r], s[r] * SCALE_);
      }
  }
#pragma unroll
  for (int i = 0; i < 16; ++i) {
    float v = m_run[i];
    v = fmaxf(v, __shfl_xor(v, 1));
    v = fmaxf(v, __shfl_xor(v, 2));
    v = fmaxf(v, __shfl_xor(v, 4));
    v = fmaxf(v, __shfl_xor(v, 8));
    m_run[i] = v;
  }
  if (ln == 0) {
#pragma unroll
    for (int mi = 0; mi < 4; ++mi)
#pragma unroll
      for (int r = 0; r < 4; ++r)
        redm[w][mi * 16 + qd * 4 + r] = m_run[mi * 4 + r];
  }
  __syncthreads();
  if (tid < 64)
    mrow[tid] = fmaxf(fmaxf(redm[0][tid], redm[1][tid]),
                      fmaxf(redm[2][tid], redm[3][tid]));
  __syncthreads();

  float l_run[16];
#pragma unroll
  for (int i = 0; i < 16; ++i) l_run[i] = 0.f;
  floatx4 oacc[4][2];
#pragma unroll
  for (int mi = 0; mi < 4; ++mi)
#pragma unroll
    for (int ni = 0; ni < 2; ++ni) {
      oacc[mi][ni][0] = 0.f; oacc[mi][ni][1] = 0.f;
      oacc[mi][ni][2] = 0.f; oacc[mi][ni][3] = 0.f;
    }
  bf16* myPs = (bf16*)Ps[w];

  for (int ch = 0; ch < nch; ++ch) {
    int tok0 = lbase + (ch << 7);
    __syncthreads();
    gld16(Kbase + (size_t)(tok0 + r0) * 32 + (c0 << 3), ldsK);
    gld16(Kbase + (size_t)(tok0 + r1) * 32 + (c1 << 3), ldsK + 512);
    gld16(Vbase + (size_t)(tok0 + r0) * 32 + (c0 << 3), ldsV);
    gld16(Vbase + (size_t)(tok0 + r1) * 32 + (c1 << 3), ldsV + 512);
    __syncthreads();
    short8 bk[2];
#pragma unroll
    for (int ni = 0; ni < 2; ++ni) {
      int r = (w << 5) + ni * 16 + ln;
      bk[ni] = *(const short8*)(Ks + (r << 5) + ((qd ^ (r & 3)) << 3));
    }
#pragma unroll
    for (int mi = 0; mi < 4; ++mi)
#pragma unroll
      for (int ni = 0; ni < 2; ++ni) {
        floatx4 s = {0.f, 0.f, 0.f, 0.f};
        s = __builtin_amdgcn_mfma_f32_16x16x32_bf16(aq[mi], bk[ni], s, 0, 0, 0);
#pragma unroll
        for (int r = 0; r < 4; ++r) {
          int row = mi * 16 + qd * 4 + r;
          float p = expf(s[r] * SCALE_ - mrow[row]);
          l_run[mi * 4 + r] += p;
          int tl = ni * 16 + ln;
          myPs[(row << 5) + (((tl >> 3) ^ (row & 3)) << 3) + (tl & 7)] = f2b(p);
        }
      }
    __syncthreads();
    short8 ap[4];
#pragma unroll
    for (int mi = 0; mi < 4; ++mi) {
      int r = mi * 16 + ln;
      ap[mi] = *(const short8*)((short*)myPs + (r << 5) + ((qd ^ (r & 3)) << 3));
    }
    short8 bv[2];
#pragma unroll
    for (int ni = 0; ni < 2; ++ni) {
      short tmp[8];
#pragma unroll
      for (int j = 0; j < 8; ++j) {
        int tok = (w << 5) + (qd << 3) + j;
        int dk = ni * 16 + ln;
        tmp[j] = Vs[(tok << 5) + (((dk >> 3) ^ (tok & 3)) << 3) + (dk & 7)];
      }
      bv[ni] = *(short8*)tmp;
    }
#pragma unroll
    for (int mi = 0; mi < 4; ++mi)
#pragma unroll
      for (int ni = 0; ni < 2; ++ni)
        oacc[mi][ni] = __builtin_amdgcn_mfma_f32_16x16x32_bf16(
            ap[mi], bv[ni], oacc[mi][ni], 0, 0, 0);
  }

#pragma unroll
  for (int i = 0; i < 16; ++i) {
    float v = l_run[i];
    v += __shfl_xor(v, 1); v += __shfl_xor(v, 2);
    v += __shfl_xor(v, 4); v += __shfl_xor(v, 8);
    l_run[i] = v;
  }
  if (ln == 0) {
#pragma unroll
    for (int mi = 0; mi < 4; ++mi)
#pragma unroll
      for (int r = 0; r < 4; ++r)
        redl[w][mi * 16 + qd * 4 + r] = l_run[mi * 4 + r];
  }
  __syncthreads();

  size_t pb = (size_t)sl * (B_ * H_) + bh;
  if (tid < UMAX_) {
    part_m[pb * UMAX_ + tid] = mrow[tid];
    part_s[pb * UMAX_ + tid] =
        redl[0][tid] + redl[1][tid] + redl[2][tid] + redl[3][tid];
  }
#pragma unroll
  for (int mi = 0; mi < 4; ++mi) {
#pragma unroll
    for (int ni = 0; ni < 2; ++ni) {
#pragma unroll
      for (int r = 0; r < 4; ++r) {
        int row = mi * 16 + qd * 4 + r;
        if (row < UMAX_) {
          int dk = ni * 16 + ln;
          part_acc[((pb * UMAX_ + row) << 7) + (w << 5) + dk] = oacc[mi][ni][r];
        }
      }
    }
  }
}

// ---------------- combine partials and scatter directly into ctx ----------
// Must run AFTER fill_ctx (which broadcasts the mean into all rows).
__global__ __launch_bounds__(256) void attn_combine_kernel(
    const float* __restrict__ part_m, const float* __restrict__ part_s,
    const float* __restrict__ part_acc, const int* __restrict__ top,
    bf16* __restrict__ ctx, int L, int u)
{
  int bh = blockIdx.x;
  int b = bh >> 3, hh = bh & 7;
  for (int i = threadIdx.x; i < u * 32; i += 256) {
    int q = i >> 5, dk = i & 31;
    float M = -3.4e38f;
#pragma unroll
    for (int s = 0; s < NS_; ++s)
      M = fmaxf(M, part_m[((size_t)s * (B_ * H_) + bh) * UMAX_ + q]);
    float num = 0.f, den = 0.f;
#pragma unroll
    for (int s = 0; s < NS_; ++s) {
      size_t pb = (size_t)s * (B_ * H_) + bh;
      float e = expf(part_m[pb * UMAX_ + q] - M);
      float a = 0.f;
#pragma unroll
      for (int w = 0; w < 4; ++w)
        a += part_acc[((pb * UMAX_ + q) << 7) + (w << 5) + dk];
      num += a * e;
      den += part_s[pb * UMAX_ + q] * e;
    }
    int lq = top[bh * u + q];
    if (lq < 0) lq = 0; if (lq >= L) lq = L - 1;
    ctx[((size_t)b * L + lq) * D_ + hh * DK_ + dk] = f2b(num / den);
  }
}

// ---------------- V mean slice partials ----------------
__global__ __launch_bounds__(256) void vmean_part_kernel(
    const bf16* __restrict__ Vh, float* __restrict__ vpart, int L)
{
  int blk = blockIdx.x;
  int bh = blk / NSV_, s = blk % NSV_;
  int tid = threadIdx.x;
  int dk = tid & 31, lg = tid >> 5;
  int Ls = L / NSV_;
  int l0 = s * Ls;
  float acc = 0.f;
  for (int l = lg; l < Ls; l += 8)
    acc += b2f(Vh[((size_t)bh * L + l0 + l) * 32 + dk]);
  __shared__ float red[256];
  red[tid] = acc;
  __syncthreads();
  for (int st = 128; st >= 32; st >>= 1) {
    if (tid < st) red[tid] += red[tid + st];
    __syncthreads();
  }
  if (tid < 32) vpart[(size_t)blk * 32 + tid] = red[tid];
}

// ---------------- ctx = broadcast mean (computed from vpart), 8 tok/block ----
__global__ __launch_bounds__(256) void fill_ctx_kernel(
    const float* __restrict__ vpart, bf16* __restrict__ ctx, int Lsh, int L)
{
  int d = threadIdx.x;
  size_t t0 = (size_t)blockIdx.x * 8;
  int b = (int)(t0 >> Lsh);
  int hh = d >> 5, dk = d & 31;
  int bh = b * H_ + hh;
  float s = 0.f;
#pragma unroll
  for (int i = 0; i < NSV_; ++i)
    s += vpart[((size_t)bh * NSV_ + i) * 32 + dk];
  bf16 v = f2b(s / (float)L);
#pragma unroll
  for (int t = 0; t < 8; ++t)
    ctx[(t0 + t) * D_ + d] = v;
}

// ---------------- h = LayerNorm(h + r): wave-per-row, no barriers ----------
__global__ __launch_bounds__(256) void add_ln_kernel(
    bf16* __restrict__ h, const bf16* __restrict__ r,
    const bf16* __restrict__ g, const bf16* __restrict__ be)
{
  int w = threadIdx.x >> 6, lane = threadIdx.x & 63;
  size_t row = (size_t)blockIdx.x * 4 + w;
  bf16* hp = h + row * D_;
  const bf16* rp = r + row * D_;
  float hv[4], rv[4];
  unpack4(*(const uint2*)(hp + lane * 4), hv);
  unpack4(*(const uint2*)(rp + lane * 4), rv);
  float v0 = hv[0] + rv[0], v1 = hv[1] + rv[1];
  float v2 = hv[2] + rv[2], v3 = hv[3] + rv[3];
  float s = v0 + v1 + v2 + v3;
#pragma unroll
  for (int off = 1; off < 64; off <<= 1) s += __shfl_xor(s, off);
  float mean = s * (1.f / D_);
  float d0 = v0 - mean, d1 = v1 - mean, d2 = v2 - mean, d3 = v3 - mean;
  float q = d0 * d0 + d1 * d1 + d2 * d2 + d3 * d3;
#pragma unroll
  for (int off = 1; off < 64; off <<= 1) q += __shfl_xor(q, off);
  float rstd = rsqrtf(q * (1.f / D_) + 1e-5f);
  float gv[4], bv[4];
  unpack4(*(const uint2*)(g + lane * 4), gv);
  unpack4(*(const uint2*)(be + lane * 4), bv);
  uint2 o;
  o.x = pack2(d0 * rstd * gv[0] + bv[0], d1 * rstd * gv[1] + bv[1]);
  o.y = pack2(d2 * rstd * gv[2] + bv[2], d3 * rstd * gv[3] + bv[3]);
  *(uint2*)(hp + lane * 4) = o;
}

// ---------------- 16B vector copy ----------------
__global__ __launch_bounds__(256) void copy16_kernel(
    uint4* __restrict__ dst, const uint4* __restrict__ src, size_t n16)
{
  size_t i = (size_t)blockIdx.x * 256 + threadIdx.x;
  if (i < n16) dst[i] = src[i];
}

// ---------------- final FC ----------------
__global__ __launch_bounds__(64) void final_fc_kernel(
    const bf16* __restrict__ h, const bf16* __restrict__ fcw,
    const bf16* __restrict__ fcb, void* __restrict__ out, int L,
    const int* __restrict__ flag)
{
  int b = blockIdx.x;
  int p = threadIdx.x;
  if (p >= PRED_) return;
  const bf16* hr = h + ((size_t)b * L + (L - 1)) * D_;
  float s = b2f(fcb[p]);
  for (int d = 0; d < D_; ++d) s += b2f(hr[d]) * b2f(fcw[d * PRED_ + p]);
  if (flag[0]) ((float*)out)[b * PRED_ + p] = s;
  else         ((bf16*)out)[b * PRED_ + p]  = f2b(s);
}

// ---------------- host ----------------
extern "C" void kernel_launch(void* const* d_in, const int* in_sizes, int n_in,
                              void* d_out, int out_size, void* d_ws, size_t ws_size,
                              hipStream_t stream)
{
  const size_t hsz = (size_t)B_ * L0_ * D_;
  char* wsc = (char*)d_ws;
  bf16* h  = (bf16*)wsc;
  bf16* Qh = (bf16*)(wsc + hsz * 2);
  bf16* Kh = (bf16*)(wsc + hsz * 4);
  bf16* Vh = (bf16*)(wsc + hsz * 6);
  char* misc = wsc + hsz * 8;
  float* Mbuf    = (float*)misc;
  float* ctx_top = Mbuf + (size_t)B_ * H_ * L0_;          // (unused, kept for layout)
  float* vmean   = ctx_top + (size_t)B_ * H_ * UMAX_ * DK_; // (unused)
  int*   topbuf  = (int*)(vmean + B_ * H_ * DK_);
  int*   flag    = topbuf + B_ * H_ * UMAX_;
  float* part_m  = (float*)(flag + 4);
  float* part_s  = part_m + (size_t)NS_ * B_ * H_ * UMAX_;
  float* part_acc= part_s + (size_t)NS_ * B_ * H_ * UMAX_;
  float* vpart   = part_acc + (size_t)NS_ * B_ * H_ * UMAX_ * 128;
  bf16*  zbuf    = (bf16*)(vpart + (size_t)B_ * H_ * NSV_ * 32);
  bf16*  canon   = zbuf + 32;

  bf16* qkvT = canon;                       // 3 layers x [768][256]
  bf16* owT  = qkvT + 3 * 196608;
  bf16* f1wT = owT  + 3 * 65536;
  bf16* f2wT = f1wT + 3 * 262144;
  bf16* cwT  = f2wT + 3 * 262144;
  bf16* smallc = cwT + 2 * 196608;

  bf16* ctxb = Vh;
  bf16* ab   = Qh;
  bf16* t1   = Kh;
  bf16* hnext = Kh;

  detect_mode_kernel<<<1, 256, 0, stream>>>((const unsigned short*)d_in[0], flag, zbuf);

  const int cidx[13] = {8, 10, 12, 14, 16, 18, 19, 20, 21, 22, 24, 25, 26};
  bf16* cptr[27] = {};
  {
    bf16* p = smallc;
    for (int t = 0; t < 13; ++t) {
      int i = cidx[t];
      int n = in_sizes[i];
      cptr[i] = p;
      canon_kernel<<<(n + 255) / 256, 256, 0, stream>>>(d_in[i], p, n, flag);
      p += (n + 7) & ~7;
    }
  }
  transpose_w_kernel<<<dim3(256, 3), 256, 0, stream>>>(d_in[7],  qkvT,          256, 256, flag, 196608);
  transpose_w_kernel<<<dim3(256, 3), 256, 0, stream>>>(d_in[9],  qkvT + 65536,  256, 256, flag, 196608);
  transpose_w_kernel<<<dim3(256, 3), 256, 0, stream>>>(d_in[11], qkvT + 131072, 256, 256, flag, 196608);
  transpose_w_kernel<<<dim3(256, 3), 256, 0, stream>>>(d_in[13], owT,  256, 256, flag, 65536);
  transpose_w_kernel<<<dim3(1024, 3), 256, 0, stream>>>(d_in[15], f1wT, 256, 1024, flag, 262144);
  transpose_w_kernel<<<dim3(1024, 3), 256, 0, stream>>>(d_in[17], f2wT, 1024, 256, flag, 262144);
  transpose_cw_kernel<<<dim3(768, 2), 256, 0, stream>>>(d_in[23], cwT, flag);

  const int* idx[3] = {(const int*)d_in[1], (const int*)d_in[2], (const int*)d_in[3]};
  int us[3] = {in_sizes[1], in_sizes[2], in_sizes[3]};

  embed_kernel<<<B_ * L0_ / 8, 256, 0, stream>>>(d_in[0], d_in[4], d_in[5], d_in[6], flag, h);

  int L = L0_;
  for (int i = 0; i < 3; ++i) {
    int tokens = B_ * L;
    int u = us[i];
    int Lsh = 31 - __builtin_clz(L);
    int rm = tokens / 128;
    mfma_gemm<0,1><<<6 * rm, 256, 0, stream>>>(
        h, qkvT + (size_t)i * 196608,
        cptr[8] + i * D_, cptr[10] + i * D_, cptr[12] + i * D_,
        Qh, tokens, 768, 256, Lsh, hsz, 6);

    prob_scores_kernel<<<B_ * H_ * (L / 256), 256, 0, stream>>>(Qh, Kh, idx[i], Mbuf, L, u);
    topk_kernel<<<B_ * H_, 256, 0, stream>>>(Mbuf, topbuf, L, u);
    topq_attn_mfma<<<dim3(B_ * H_, NS_), 256, 0, stream>>>(
        Qh, Kh, Vh, topbuf, part_m, part_s, part_acc, L, u);
    vmean_part_kernel<<<B_ * H_ * NSV_, 256, 0, stream>>>(Vh, vpart, L);
    // ctxb aliases Vh; both readers of Vh (topq_attn, vmean_part) are done.
    fill_ctx_kernel<<<tokens / 8, 256, 0, stream>>>(vpart, ctxb, Lsh, L);
    attn_combine_kernel<<<B_ * H_, 256, 0, stream>>>(
        part_m, part_s, part_acc, topbuf, ctxb, L, u);
    mfma_gemm<0,0><<<2 * rm, 256, 0, stream>>>(
        ctxb, owT + (size_t)i * 65536, cptr[14] + i * D_, nullptr, nullptr,
        ab, tokens, 256, 256, 0, 0, 2);

    add_ln_kernel<<<tokens / 4, 256, 0, stream>>>(h, ab, cptr[19] + i * D_, cptr[20] + i * D_);

    const int CH = 16384;
    for (int c0 = 0; c0 < tokens; c0 += CH) {
      int cm = (tokens - c0 < CH) ? (tokens - c0) : CH;
      int rmc = cm / 128;
      mfma_gemm<1,0><<<8 * rmc, 256, 0, stream>>>(
          h + (size_t)c0 * D_, f1wT + (size_t)i * 262144, cptr[16] + i * FF_,
          nullptr, nullptr, t1, cm, FF_, 256, 0, 0, 8);
      mfma_gemm<0,0><<<2 * rmc, 256, 0, stream>>>(
          t1, f2wT + (size_t)i * 262144, cptr[18] + i * D_, nullptr, nullptr,
          ab + (size_t)c0 * D_, cm, 256, FF_, 0, 0, 2);
    }
    add_ln_kernel<<<tokens / 4, 256, 0, stream>>>(h, ab, cptr[21] + i * D_, cptr[22] + i * D_);

    if (i < 2) {
      int Lh = L / 2;
      mfma_conv_distill<<<2 * (B_ * (L / 128)), 256, 0, stream>>>(
          h, cwT + (size_t)i * 196608, cptr[24] + i * D_, hnext, zbuf, L);
      size_t n16 = (size_t)B_ * Lh * D_ / 8;
      copy16_kernel<<<(unsigned)((n16 + 255) / 256), 256, 0, stream>>>(
          (uint4*)h, (const uint4*)hnext, n16);
      L = Lh;
    }
  }
  final_fc_kernel<<<B_, 64, 0, stream>>>(h, cptr[25], cptr[26], d_out, L, flag);
}

// Round 15
// 1159.932 us; speedup vs baseline: 1.0897x; 1.0897x over previous
//
#include <hip/hip_runtime.h>
#include <hip/hip_bf16.h>
#include <math.h>

typedef __hip_bfloat16 bf16;
typedef __attribute__((ext_vector_type(8))) short short8;
typedef __attribute__((ext_vector_type(4))) float floatx4;

#define B_    16
#define L0_   4096
#define IN_   8
#define D_    256
#define H_    8
#define DK_   32
#define FF_   1024
#define PRED_ 24
#define UMAX_ 48
#define NS_   4
#define NSV_  8
#define SCALE_ 0.17677669529663687f   // 1/sqrt(32)

__device__ __forceinline__ float b2f(bf16 v) { return __bfloat162float(v); }
__device__ __forceinline__ bf16  f2b(float v){ return __float2bfloat16(v); }
__device__ __forceinline__ float gelu_exact(float x){
  return 0.5f * x * (1.0f + erff(x * 0.7071067811865476f));
}
__device__ __forceinline__ float eluf(float x){ return x > 0.f ? x : (expf(x) - 1.f); }
__device__ __forceinline__ float ldf(const void* p, size_t i, int f){
  return f ? ((const float*)p)[i] : b2f(((const bf16*)p)[i]);
}
__device__ __forceinline__ void gld16(const void* g, const short* l){
  __builtin_amdgcn_global_load_lds(
      (const __attribute__((address_space(1))) unsigned int*)g,
      (__attribute__((address_space(3))) unsigned int*)l, 16, 0, 0);
}
__device__ __forceinline__ void unpack8(uint4 v, float* o){
  o[0] = __uint_as_float(v.x << 16); o[1] = __uint_as_float(v.x & 0xffff0000u);
  o[2] = __uint_as_float(v.y << 16); o[3] = __uint_as_float(v.y & 0xffff0000u);
  o[4] = __uint_as_float(v.z << 16); o[5] = __uint_as_float(v.z & 0xffff0000u);
  o[6] = __uint_as_float(v.w << 16); o[7] = __uint_as_float(v.w & 0xffff0000u);
}
__device__ __forceinline__ void unpack4(uint2 v, float* o){
  o[0] = __uint_as_float(v.x << 16); o[1] = __uint_as_float(v.x & 0xffff0000u);
  o[2] = __uint_as_float(v.y << 16); o[3] = __uint_as_float(v.y & 0xffff0000u);
}
__device__ __forceinline__ unsigned pack2(float a, float b){
  bf16 x = f2b(a), y = f2b(b);
  return (unsigned)*(unsigned short*)&x | ((unsigned)*(unsigned short*)&y << 16);
}
__device__ __forceinline__ void ld_row32(const bf16* p, float* o){
  const uint4* q = (const uint4*)p;
  uint4 a = q[0], b = q[1], c = q[2], d = q[3];
  unpack8(a, o); unpack8(b, o + 8); unpack8(c, o + 16); unpack8(d, o + 24);
}

// ---------------- dtype detector (+ zero scratch init) ----------------
__global__ __launch_bounds__(256) void detect_mode_kernel(
    const unsigned short* __restrict__ x16, int* __restrict__ flag,
    bf16* __restrict__ zbuf)
{
  int tid = threadIdx.x;
  if (tid < 32) zbuf[tid] = f2b(0.f);
  int cnt = 0;
  for (int i = tid; i < 512; i += 256) {
    unsigned short v = x16[2 * i];
    int expo = (v >> 7) & 0xFF;
    if (expo >= 0x90) cnt++;
  }
  __shared__ int red[256];
  red[tid] = cnt;
  __syncthreads();
  for (int s = 128; s > 0; s >>= 1) {
    if (tid < s) red[tid] += red[tid + s];
    __syncthreads();
  }
  if (tid == 0) flag[0] = (red[0] > 8) ? 1 : 0;
}

// ---------------- canonicalize one array to bf16 ----------------
__global__ __launch_bounds__(256) void canon_kernel(
    const void* __restrict__ src, bf16* __restrict__ dst, int n,
    const int* __restrict__ flag)
{
  int i = blockIdx.x * 256 + threadIdx.x;
  if (i >= n) return;
  dst[i] = f2b(ldf(src, i, flag[0]));
}

// ---------------- transpose weight [K][N] -> [N][K], per layer ----------------
__global__ __launch_bounds__(256) void transpose_w_kernel(
    const void* __restrict__ src, bf16* __restrict__ dst, int K, int N,
    const int* __restrict__ flag, int lstride)
{
  int i = blockIdx.x * 256 + threadIdx.x;
  if (i >= K * N) return;
  size_t soff = (size_t)blockIdx.y * K * N;
  int k = i / N, n = i % N;
  dst[(size_t)blockIdx.y * lstride + (size_t)n * K + k] = f2b(ldf(src, soff + i, flag[0]));
}

// ---------------- conv weight [o][c][3] -> [t][o][c], per layer ----------------
__global__ __launch_bounds__(256) void transpose_cw_kernel(
    const void* __restrict__ src, bf16* __restrict__ dst,
    const int* __restrict__ flag)
{
  int i = blockIdx.x * 256 + threadIdx.x;
  if (i >= D_ * D_ * 3) return;
  size_t off = (size_t)blockIdx.y * D_ * D_ * 3;
  int o = i / (D_ * 3), c = (i / 3) % D_, t = i % 3;
  dst[off + ((size_t)t * D_ + o) * D_ + c] = f2b(ldf(src, off + i, flag[0]));
}

// ---------------- embed: 8 tokens per block ----------------
__global__ __launch_bounds__(256) void embed_kernel(
    const void* __restrict__ x, const void* __restrict__ in_w,
    const void* __restrict__ in_b, const void* __restrict__ pos,
    const int* __restrict__ flag, bf16* __restrict__ h)
{
  int d = threadIdx.x;
  int f = flag[0];
  float wcol[IN_];
#pragma unroll
  for (int k = 0; k < IN_; ++k) wcol[k] = ldf(in_w, k * D_ + d, f);
  float bd = ldf(in_b, d, f);
  int t0 = blockIdx.x * 8;
#pragma unroll
  for (int t = 0; t < 8; ++t) {
    int token = t0 + t;
    int l = token & (L0_ - 1);
    float s = bd + ldf(pos, (size_t)l * D_ + d, f);
#pragma unroll
    for (int k = 0; k < IN_; ++k)
      s += ldf(x, (size_t)token * IN_ + k, f) * wcol[k];
    h[(size_t)token * D_ + d] = f2b(s);
  }
}

// ---------------- MFMA GEMM (BK=64, XCD-aware 1D swizzle, direct stores) ----
// grid = cn * rm (1-D). c = (id>>3)%cn, r = (id&7) + 8*((id>>3)/cn).
// HM=0: C token-major [M][N], bias=b0. HM=1: merged QKV head-major; N=768.
// NOTE: direct scalar epilogue stores — LDS-transposed epilogue was tried
// twice (R12, R14) and regressed both times; store shape is not a bottleneck
// on gfx950, fetch locality is.
template<int ACT, int HM>
__global__ __launch_bounds__(256) void mfma_gemm(
    const bf16* __restrict__ A, const bf16* __restrict__ Wt,
    const bf16* __restrict__ b0, const bf16* __restrict__ b1,
    const bf16* __restrict__ b2, bf16* __restrict__ C,
    int M, int N, int K, int Lsh, size_t partStride, int cn)
{
  __shared__ short As[128 * 64];
  __shared__ short Bs[128 * 64];
  int tid = threadIdx.x;
  int w = tid >> 6, lane = tid & 63;
  int ln = lane & 15, qd = lane >> 4;
  int id = blockIdx.x;
  int idx = id >> 3;
  int cblk = idx % cn;
  int rblk = (id & 7) + ((idx / cn) << 3);
  int bm = rblk << 7, bn = cblk << 7;
  int wm = (w >> 1) << 6, wn = (w & 1) << 6;

  floatx4 acc[4][4];
#pragma unroll
  for (int mi = 0; mi < 4; ++mi)
#pragma unroll
    for (int ni = 0; ni < 4; ++ni) {
      acc[mi][ni][0] = 0.f; acc[mi][ni][1] = 0.f;
      acc[mi][ni][2] = 0.f; acc[mi][ni][3] = 0.f;
    }

  int rr[4], ofs[4];
#pragma unroll
  for (int t = 0; t < 4; ++t) {
    int p = (w << 8) + (t << 6) + lane;
    int r = p >> 3;
    ofs[t] = (((p & 7) ^ (r & 7)) << 3);
    rr[t] = r;
  }
  const bf16* pA[4]; const bf16* pB[4]; short* dst[4];
#pragma unroll
  for (int t = 0; t < 4; ++t) {
    pA[t] = A + (size_t)(bm + rr[t]) * K + ofs[t];
    pB[t] = Wt + (size_t)(bn + rr[t]) * K + ofs[t];
    dst[t] = As + (((w << 2) + t) << 9);
  }

  for (int k0 = 0; k0 < K; k0 += 64) {
    __syncthreads();
#pragma unroll
    for (int t = 0; t < 4; ++t) gld16(pA[t] + k0, dst[t]);
#pragma unroll
    for (int t = 0; t < 4; ++t) gld16(pB[t] + k0, dst[t] + 128 * 64);
    __syncthreads();
#pragma unroll
    for (int kb = 0; kb < 2; ++kb) {
      short8 af[4], bff[4];
#pragma unroll
      for (int mi = 0; mi < 4; ++mi) {
        int r = wm + mi * 16 + ln;
        af[mi] = *(const short8*)(As + (r << 6) + ((((kb << 2) + qd) ^ (r & 7)) << 3));
      }
#pragma unroll
      for (int ni = 0; ni < 4; ++ni) {
        int r = wn + ni * 16 + ln;
        bff[ni] = *(const short8*)(Bs + (r << 6) + ((((kb << 2) + qd) ^ (r & 7)) << 3));
      }
#pragma unroll
      for (int mi = 0; mi < 4; ++mi)
#pragma unroll
        for (int ni = 0; ni < 4; ++ni)
          acc[mi][ni] = __builtin_amdgcn_mfma_f32_16x16x32_bf16(
              af[mi], bff[ni], acc[mi][ni], 0, 0, 0);
    }
  }

#pragma unroll
  for (int ni = 0; ni < 4; ++ni) {
    int col = bn + wn + ni * 16 + ln;
    const bf16* bsel = b0;
    int cm = col;
    if (HM) {
      int part = col >> 8;
      cm = col & 255;
      bsel = (part == 0) ? b0 : ((part == 1) ? b1 : b2);
    }
    float bv = b2f(bsel[cm]);
    int part = HM ? (col >> 8) : 0;
    int hh = cm >> 5, dk = cm & 31;
#pragma unroll
    for (int mi = 0; mi < 4; ++mi) {
      int row = bm + wm + mi * 16 + (qd << 2);
#pragma unroll
      for (int r = 0; r < 4; ++r) {
        float v = acc[mi][ni][r] + bv;
        if (ACT == 1) v = gelu_exact(v);
        if (HM) {
          int rr2 = row + r;
          int bb = rr2 >> Lsh, ll = rr2 & ((1 << Lsh) - 1);
          C[part * partStride + ((((size_t)(bb * H_ + hh)) << Lsh) + ll) * 32 + dk] = f2b(v);
        } else {
          C[(size_t)(row + r) * N + col] = f2b(v);
        }
      }
    }
  }
}

// ---------------- MFMA fused conv3(pad1)+bias+ELU+maxpool2 (BK=32) ----------------
__global__ __launch_bounds__(256) void mfma_conv_distill(
    const bf16* __restrict__ hsrc, const bf16* __restrict__ WtC,
    const bf16* __restrict__ cb, bf16* __restrict__ outp,
    const bf16* __restrict__ zbuf, int L)
{
  __shared__ short As[128 * 32];
  __shared__ short Bs[128 * 32];
  int tid = threadIdx.x;
  int w = tid >> 6, lane = tid & 63;
  int ln = lane & 15, qd = lane >> 4;
  int id = blockIdx.x;
  int idx = id >> 3;
  int cblk = idx & 1;
  int rblk = (id & 7) + ((idx >> 1) << 3);
  int bn = cblk << 7;
  int bpb = L >> 7;
  int b = rblk / bpb;
  int p0 = (rblk % bpb) << 7;
  int wm = (w >> 1) << 6, wn = (w & 1) << 6;

  floatx4 acc[4][4];
#pragma unroll
  for (int mi = 0; mi < 4; ++mi)
#pragma unroll
    for (int ni = 0; ni < 4; ++ni) {
      acc[mi][ni][0] = 0.f; acc[mi][ni][1] = 0.f;
      acc[mi][ni][2] = 0.f; acc[mi][ni][3] = 0.f;
    }

  int s0 = (w << 7) + lane, s1 = s0 + 64;
  int r0 = s0 >> 2, c0 = (s0 & 3) ^ (r0 & 3);
  int r1 = s1 >> 2, c1 = (s1 & 3) ^ (r1 & 3);
  short* ldsA = As + (w << 10);
  short* ldsB = Bs + (w << 10);

  for (int tap = 0; tap < 3; ++tap) {
    const bf16* wt = WtC + (size_t)tap * D_ * D_;
    int pos0 = p0 + r0 + tap - 1;
    int pos1 = p0 + r1 + tap - 1;
    const bf16* gA0 = (pos0 >= 0 && pos0 < L)
        ? hsrc + ((size_t)b * L + pos0) * D_ + (c0 << 3) : zbuf;
    const bf16* gA1 = (pos1 >= 0 && pos1 < L)
        ? hsrc + ((size_t)b * L + pos1) * D_ + (c1 << 3) : zbuf;
    int stepA0 = (pos0 >= 0 && pos0 < L) ? 1 : 0;
    int stepA1 = (pos1 >= 0 && pos1 < L) ? 1 : 0;
    const bf16* gB0 = wt + (size_t)(bn + r0) * D_ + (c0 << 3);
    const bf16* gB1 = wt + (size_t)(bn + r1) * D_ + (c1 << 3);
    for (int k0 = 0; k0 < D_; k0 += 32) {
      __syncthreads();
      gld16(gA0 + (size_t)k0 * stepA0, ldsA);
      gld16(gA1 + (size_t)k0 * stepA1, ldsA + 512);
      gld16(gB0 + k0, ldsB);
      gld16(gB1 + k0, ldsB + 512);
      __syncthreads();
      short8 af[4], bff[4];
#pragma unroll
      for (int mi = 0; mi < 4; ++mi) {
        int r = wm + mi * 16 + ln;
        af[mi] = *(const short8*)(As + (r << 5) + ((qd ^ (r & 3)) << 3));
      }
#pragma unroll
      for (int ni = 0; ni < 4; ++ni) {
        int r = wn + ni * 16 + ln;
        bff[ni] = *(const short8*)(Bs + (r << 5) + ((qd ^ (r & 3)) << 3));
      }
#pragma unroll
      for (int mi = 0; mi < 4; ++mi)
#pragma unroll
        for (int ni = 0; ni < 4; ++ni)
          acc[mi][ni] = __builtin_amdgcn_mfma_f32_16x16x32_bf16(
              af[mi], bff[ni], acc[mi][ni], 0, 0, 0);
    }
  }

  int Lh = L >> 1;
#pragma unroll
  for (int ni = 0; ni < 4; ++ni) {
    int col = bn + wn + ni * 16 + ln;
    float bv = b2f(cb[col]);
#pragma unroll
    for (int mi = 0; mi < 4; ++mi) {
      float y0 = eluf(acc[mi][ni][0] + bv);
      float y1 = eluf(acc[mi][ni][1] + bv);
      float y2 = eluf(acc[mi][ni][2] + bv);
      float y3 = eluf(acc[mi][ni][3] + bv);
      int prow = (p0 + wm + mi * 16 + (qd << 2)) >> 1;
      outp[((size_t)b * Lh + prow) * D_ + col]     = f2b(fmaxf(y0, y1));
      outp[((size_t)b * Lh + prow + 1) * D_ + col] = f2b(fmaxf(y2, y3));
    }
  }
}

// ---------------- ProbSparse M scores (K[idx] staged in LDS, float4 dots) ----
__global__ __launch_bounds__(256) void prob_scores_kernel(
    const bf16* __restrict__ Qh, const bf16* __restrict__ Kh,
    const int* __restrict__ idx, float* __restrict__ Mout, int L, int u)
{
  __shared__ float ks[UMAX_][32];
  int tid = threadIdx.x;
  int bpb = L >> 8;
  int bh = blockIdx.x / bpb;
  int l  = (blockIdx.x % bpb) * 256 + tid;
  if (tid < u * 4) {
    int t = tid >> 2, c = tid & 3;
    int ls = idx[t];
    if (ls < 0) ls = 0; if (ls >= L) ls = L - 1;
    uint4 v = *(const uint4*)(Kh + ((size_t)bh * L + ls) * 32 + c * 8);
    unpack8(v, &ks[t][c * 8]);
  }
  __syncthreads();
  float qv[32];
  ld_row32(Qh + ((size_t)bh * L + l) * 32, qv);
  float mx = -3.4e38f, sm = 0.f;
  for (int t = 0; t < u; ++t) {
    float s = 0.f;
#pragma unroll
    for (int j4 = 0; j4 < 8; ++j4) {
      float4 k4 = *(const float4*)&ks[t][j4 * 4];
      s += qv[4*j4+0]*k4.x + qv[4*j4+1]*k4.y + qv[4*j4+2]*k4.z + qv[4*j4+3]*k4.w;
    }
    s *= SCALE_;
    mx = fmaxf(mx, s);
    sm += s;
  }
  Mout[(size_t)bh * L + l] = mx - sm / (float)u;
}

// ---------------- top-k: radix-select (order-free set semantics) ----------
__global__ __launch_bounds__(256) void topk_kernel(
    const float* __restrict__ M, int* __restrict__ top, int L, int u)
{
  __shared__ unsigned int hist[256];
  __shared__ unsigned int prefS, kS;
  __shared__ int cntG, tieCnt;
  __shared__ int tieList[256];
  int bh = blockIdx.x;
  int tid = threadIdx.x;
  int w = tid >> 6, lane = tid & 63;
  int nper = L >> 8;

  unsigned int key[16];
  for (int i = 0; i < nper; ++i) {
    unsigned int ub = __float_as_uint(M[(size_t)bh * L + i * 256 + tid]);
    key[i] = (ub & 0x80000000u) ? ~ub : (ub | 0x80000000u);
  }

  unsigned int pref = 0, k = (unsigned int)u;
  for (int round = 0; round < 4; ++round) {
    int shift = 24 - (round << 3);
    hist[tid] = 0;
    __syncthreads();
    for (int i = 0; i < nper; ++i) {
      unsigned int kk = key[i];
      if (round == 0 || (kk >> (shift + 8)) == pref)
        atomicAdd(&hist[(kk >> shift) & 0xFFu], 1u);
    }
    __syncthreads();
    if (w == 0) {
      int d0 = lane << 2;
      unsigned int h0 = hist[d0], h1 = hist[d0 + 1];
      unsigned int h2 = hist[d0 + 2], h3 = hist[d0 + 3];
      unsigned int lsum = h0 + h1 + h2 + h3;
      unsigned int incl = lsum;
#pragma unroll
      for (int off = 1; off < 64; off <<= 1) {
        unsigned int o = __shfl_down(incl, off);
        if (lane + off < 64) incl += o;
      }
      unsigned int e3 = incl - lsum;
      unsigned int e2 = e3 + h3;
      unsigned int e1 = e2 + h2;
      unsigned int e0 = e1 + h1;
      if (e3 < k && k <= e3 + h3) { prefS = (pref << 8) | (d0 + 3); kS = k - e3; }
      if (e2 < k && k <= e2 + h2) { prefS = (pref << 8) | (d0 + 2); kS = k - e2; }
      if (e1 < k && k <= e1 + h1) { prefS = (pref << 8) | (d0 + 1); kS = k - e1; }
      if (e0 < k && k <= e0 + h0) { prefS = (pref << 8) | (d0 + 0); kS = k - e0; }
    }
    __syncthreads();
    pref = prefS;
    k = kS;
    __syncthreads();
  }

  unsigned int T = pref;
  if (tid == 0) { cntG = 0; tieCnt = 0; }
  __syncthreads();
  for (int i = 0; i < nper; ++i) {
    unsigned int kk = key[i];
    int lidx = i * 256 + tid;
    if (kk > T) {
      int pos = atomicAdd(&cntG, 1);
      if (pos < u) top[bh * u + pos] = lidx;
    } else if (kk == T) {
      int tpos = atomicAdd(&tieCnt, 1);
      if (tpos < 256) tieList[tpos] = lidx;
    }
  }
  __syncthreads();
  if (tid == 0) {
    int base = cntG;
    int E = tieCnt; if (E > 256) E = 256;
    for (int t = 0; t < (int)k && base + t < u; ++t) {
      int best = 0x7fffffff, bj = -1;
      for (int j = 0; j < E; ++j) {
        int v = tieList[j];
        if (v >= 0 && v < best) { best = v; bj = j; }
      }
      if (bj >= 0) { tieList[bj] = -1; top[bh * u + base + t] = best; }
      else top[bh * u + base + t] = 0;
    }
  }
}

// ---------------- topq attention: MFMA flash, per (b,h,slice) ----------------
__global__ __launch_bounds__(256) void topq_attn_mfma(
    const bf16* __restrict__ Qh, const bf16* __restrict__ Kh,
    const bf16* __restrict__ Vh, const int* __restrict__ top,
    float* __restrict__ part_m, float* __restrict__ part_s,
    float* __restrict__ part_acc, int L, int u)
{
  __shared__ short Qs[64 * 32];
  __shared__ short Ks[128 * 32];
  __shared__ short Vs[128 * 32];
  __shared__ short Ps[4][64 * 32];
  __shared__ float mrow[64];
  __shared__ float redm[4][64];
  __shared__ float redl[4][64];

  int bh = blockIdx.x, sl = blockIdx.y;
  int tid = threadIdx.x;
  int w = tid >> 6, lane = tid & 63;
  int ln = lane & 15, qd = lane >> 4;
  int Ls = L / NS_;
  int lbase = sl * Ls;
  const bf16* Kbase = Kh + (size_t)bh * L * 32;
  const bf16* Vbase = Vh + (size_t)bh * L * 32;

  {
    int r = tid >> 2, cpos = tid & 3, corig = cpos ^ (r & 3);
    uint4 v = make_uint4(0, 0, 0, 0);
    if (r < u) {
      int lq = top[bh * u + r];
      if (lq < 0) lq = 0; if (lq >= L) lq = L - 1;
      v = *(const uint4*)(Qh + ((size_t)bh * L + lq) * 32 + corig * 8);
    }
    *(uint4*)(Qs + r * 32 + cpos * 8) = v;
  }
  __syncthreads();

  short8 aq[4];
#pragma unroll
  for (int mi = 0; mi < 4; ++mi) {
    int r = mi * 16 + ln;
    aq[mi] = *(const short8*)(Qs + (r << 5) + ((qd ^ (r & 3)) << 3));
  }

  int s0 = (w << 7) + lane, s1 = s0 + 64;
  int r0 = s0 >> 2, c0 = (s0 & 3) ^ (r0 & 3);
  int r1 = s1 >> 2, c1 = (s1 & 3) ^ (r1 & 3);
  short* ldsK = Ks + (w << 10);
  short* ldsV = Vs + (w << 10);
  int nch = Ls >> 7;

  float m_run[16];
#pragma unroll
  for (int i = 0; i < 16; ++i) m_run[i] = -3.4e38f;

  for (int ch = 0; ch < nch; ++ch) {
    int tok0 = lbase + (ch << 7);
    __syncthreads();
    gld16(Kbase + (size_t)(tok0 + r0) * 32 + (c0 << 3), ldsK);
    gld16(Kbase + (size_t)(tok0 + r1) * 32 + (c1 << 3), ldsK + 512);
    __syncthreads();
    short8 bk[2];
#pragma unroll
    for (int ni = 0; ni < 2; ++ni) {
      int r = (w << 5) + ni * 16 + ln;
      bk[ni] = *(const short8*)(Ks + (r << 5) + ((qd ^ (r & 3)) << 3));
    }
#pragma unroll
    for (int mi = 0; mi < 4; ++mi)
#pragma unroll
      for (int ni = 0; ni < 2; ++ni) {
        floatx4 s = {0.f, 0.f, 0.f, 0.f};
        s = __builtin_amdgcn_mfma_f32_16x16x32_bf16(aq[mi], bk[ni], s, 0, 0, 0);
#pragma unroll
        for (int r = 0; r < 4; ++r)
          m_run[mi * 4 + r] = fmaxf(m_run[mi * 4 + r], s[r] * SCALE_);
      }
  }
#pragma unroll
  for (int i = 0; i < 16; ++i) {
    float v = m_run[i];
    v = fmaxf(v, __shfl_xor(v, 1));
    v = fmaxf(v, __shfl_xor(v, 2));
    v = fmaxf(v, __shfl_xor(v, 4));
    v = fmaxf(v, __shfl_xor(v, 8));
    m_run[i] = v;
  }
  if (ln == 0) {
#pragma unroll
    for (int mi = 0; mi < 4; ++mi)
#pragma unroll
      for (int r = 0; r < 4; ++r)
        redm[w][mi * 16 + qd * 4 + r] = m_run[mi * 4 + r];
  }
  __syncthreads();
  if (tid < 64)
    mrow[tid] = fmaxf(fmaxf(redm[0][tid], redm[1][tid]),
                      fmaxf(redm[2][tid], redm[3][tid]));
  __syncthreads();

  float l_run[16];
#pragma unroll
  for (int i = 0; i < 16; ++i) l_run[i] = 0.f;
  floatx4 oacc[4][2];
#pragma unroll
  for (int mi = 0; mi < 4; ++mi)
#pragma unroll
    for (int ni = 0; ni < 2; ++ni) {
      oacc[mi][ni][0] = 0.f; oacc[mi][ni][1] = 0.f;
      oacc[mi][ni][2] = 0.f; oacc[mi][ni][3] = 0.f;
    }
  bf16* myPs = (bf16*)Ps[w];

  for (int ch = 0; ch < nch; ++ch) {
    int tok0 = lbase + (ch << 7);
    __syncthreads();
    gld16(Kbase + (size_t)(tok0 + r0) * 32 + (c0 << 3), ldsK);
    gld16(Kbase + (size_t)(tok0 + r1) * 32 + (c1 << 3), ldsK + 512);
    gld16(Vbase + (size_t)(tok0 + r0) * 32 + (c0 << 3), ldsV);
    gld16(Vbase + (size_t)(tok0 + r1) * 32 + (c1 << 3), ldsV + 512);
    __syncthreads();
    short8 bk[2];
#pragma unroll
    for (int ni = 0; ni < 2; ++ni) {
      int r = (w << 5) + ni * 16 + ln;
      bk[ni] = *(const short8*)(Ks + (r << 5) + ((qd ^ (r & 3)) << 3));
    }
#pragma unroll
    for (int mi = 0; mi < 4; ++mi)
#pragma unroll
      for (int ni = 0; ni < 2; ++ni) {
        floatx4 s = {0.f, 0.f, 0.f, 0.f};
        s = __builtin_amdgcn_mfma_f32_16x16x32_bf16(aq[mi], bk[ni], s, 0, 0, 0);
#pragma unroll
        for (int r = 0; r < 4; ++r) {
          int row = mi * 16 + qd * 4 + r;
          float p = expf(s[r] * SCALE_ - mrow[row]);
          l_run[mi * 4 + r] += p;
          int tl = ni * 16 + ln;
          myPs[(row << 5) + (((tl >> 3) ^ (row & 3)) << 3) + (tl & 7)] = f2b(p);
        }
      }
    __syncthreads();
    short8 ap[4];
#pragma unroll
    for (int mi = 0; mi < 4; ++mi) {
      int r = mi * 16 + ln;
      ap[mi] = *(const short8*)((short*)myPs + (r << 5) + ((qd ^ (r & 3)) << 3));
    }
    short8 bv[2];
#pragma unroll
    for (int ni = 0; ni < 2; ++ni) {
      short tmp[8];
#pragma unroll
      for (int j = 0; j < 8; ++j) {
        int tok = (w << 5) + (qd << 3) + j;
        int dk = ni * 16 + ln;
        tmp[j] = Vs[(tok << 5) + (((dk >> 3) ^ (tok & 3)) << 3) + (dk & 7)];
      }
      bv[ni] = *(short8*)tmp;
    }
#pragma unroll
    for (int mi = 0; mi < 4; ++mi)
#pragma unroll
      for (int ni = 0; ni < 2; ++ni)
        oacc[mi][ni] = __builtin_amdgcn_mfma_f32_16x16x32_bf16(
            ap[mi], bv[ni], oacc[mi][ni], 0, 0, 0);
  }

#pragma unroll
  for (int i = 0; i < 16; ++i) {
    float v = l_run[i];
    v += __shfl_xor(v, 1); v += __shfl_xor(v, 2);
    v += __shfl_xor(v, 4); v += __shfl_xor(v, 8);
    l_run[i] = v;
  }
  if (ln == 0) {
#pragma unroll
    for (int mi = 0; mi < 4; ++mi)
#pragma unroll
      for (int r = 0; r < 4; ++r)
        redl[w][mi * 16 + qd * 4 + r] = l_run[mi * 4 + r];
  }
  __syncthreads();

  size_t pb = (size_t)sl * (B_ * H_) + bh;
  if (tid < UMAX_) {
    part_m[pb * UMAX_ + tid] = mrow[tid];
    part_s[pb * UMAX_ + tid] =
        redl[0][tid] + redl[1][tid] + redl[2][tid] + redl[3][tid];
  }
#pragma unroll
  for (int mi = 0; mi < 4; ++mi) {
#pragma unroll
    for (int ni = 0; ni < 2; ++ni) {
#pragma unroll
      for (int r = 0; r < 4; ++r) {
        int row = mi * 16 + qd * 4 + r;
        if (row < UMAX_) {
          int dk = ni * 16 + ln;
          part_acc[((pb * UMAX_ + row) << 7) + (w << 5) + dk] = oacc[mi][ni][r];
        }
      }
    }
  }
}

// ---------------- combine partials and scatter directly into ctx ----------
// Must run AFTER fill_ctx (which broadcasts the mean into all rows).
__global__ __launch_bounds__(256) void attn_combine_kernel(
    const float* __restrict__ part_m, const float* __restrict__ part_s,
    const float* __restrict__ part_acc, const int* __restrict__ top,
    bf16* __restrict__ ctx, int L, int u)
{
  int bh = blockIdx.x;
  int b = bh >> 3, hh = bh & 7;
  for (int i = threadIdx.x; i < u * 32; i += 256) {
    int q = i >> 5, dk = i & 31;
    float M = -3.4e38f;
#pragma unroll
    for (int s = 0; s < NS_; ++s)
      M = fmaxf(M, part_m[((size_t)s * (B_ * H_) + bh) * UMAX_ + q]);
    float num = 0.f, den = 0.f;
#pragma unroll
    for (int s = 0; s < NS_; ++s) {
      size_t pb = (size_t)s * (B_ * H_) + bh;
      float e = expf(part_m[pb * UMAX_ + q] - M);
      float a = 0.f;
#pragma unroll
      for (int w = 0; w < 4; ++w)
        a += part_acc[((pb * UMAX_ + q) << 7) + (w << 5) + dk];
      num += a * e;
      den += part_s[pb * UMAX_ + q] * e;
    }
    int lq = top[bh * u + q];
    if (lq < 0) lq = 0; if (lq >= L) lq = L - 1;
    ctx[((size_t)b * L + lq) * D_ + hh * DK_ + dk] = f2b(num / den);
  }
}

// ---------------- V mean slice partials ----------------
__global__ __launch_bounds__(256) void vmean_part_kernel(
    const bf16* __restrict__ Vh, float* __restrict__ vpart, int L)
{
  int blk = blockIdx.x;
  int bh = blk / NSV_, s = blk % NSV_;
  int tid = threadIdx.x;
  int dk = tid & 31, lg = tid >> 5;
  int Ls = L / NSV_;
  int l0 = s * Ls;
  float acc = 0.f;
  for (int l = lg; l < Ls; l += 8)
    acc += b2f(Vh[((size_t)bh * L + l0 + l) * 32 + dk]);
  __shared__ float red[256];
  red[tid] = acc;
  __syncthreads();
  for (int st = 128; st >= 32; st >>= 1) {
    if (tid < st) red[tid] += red[tid + st];
    __syncthreads();
  }
  if (tid < 32) vpart[(size_t)blk * 32 + tid] = red[tid];
}

// ---------------- ctx = broadcast mean (computed from vpart), 8 tok/block ----
__global__ __launch_bounds__(256) void fill_ctx_kernel(
    const float* __restrict__ vpart, bf16* __restrict__ ctx, int Lsh, int L)
{
  int d = threadIdx.x;
  size_t t0 = (size_t)blockIdx.x * 8;
  int b = (int)(t0 >> Lsh);
  int hh = d >> 5, dk = d & 31;
  int bh = b * H_ + hh;
  float s = 0.f;
#pragma unroll
  for (int i = 0; i < NSV_; ++i)
    s += vpart[((size_t)bh * NSV_ + i) * 32 + dk];
  bf16 v = f2b(s / (float)L);
#pragma unroll
  for (int t = 0; t < 8; ++t)
    ctx[(t0 + t) * D_ + d] = v;
}

// ---------------- h = LayerNorm(h + r): wave-per-row, no barriers ----------
__global__ __launch_bounds__(256) void add_ln_kernel(
    bf16* __restrict__ h, const bf16* __restrict__ r,
    const bf16* __restrict__ g, const bf16* __restrict__ be)
{
  int w = threadIdx.x >> 6, lane = threadIdx.x & 63;
  size_t row = (size_t)blockIdx.x * 4 + w;
  bf16* hp = h + row * D_;
  const bf16* rp = r + row * D_;
  float hv[4], rv[4];
  unpack4(*(const uint2*)(hp + lane * 4), hv);
  unpack4(*(const uint2*)(rp + lane * 4), rv);
  float v0 = hv[0] + rv[0], v1 = hv[1] + rv[1];
  float v2 = hv[2] + rv[2], v3 = hv[3] + rv[3];
  float s = v0 + v1 + v2 + v3;
#pragma unroll
  for (int off = 1; off < 64; off <<= 1) s += __shfl_xor(s, off);
  float mean = s * (1.f / D_);
  float d0 = v0 - mean, d1 = v1 - mean, d2 = v2 - mean, d3 = v3 - mean;
  float q = d0 * d0 + d1 * d1 + d2 * d2 + d3 * d3;
#pragma unroll
  for (int off = 1; off < 64; off <<= 1) q += __shfl_xor(q, off);
  float rstd = rsqrtf(q * (1.f / D_) + 1e-5f);
  float gv[4], bv[4];
  unpack4(*(const uint2*)(g + lane * 4), gv);
  unpack4(*(const uint2*)(be + lane * 4), bv);
  uint2 o;
  o.x = pack2(d0 * rstd * gv[0] + bv[0], d1 * rstd * gv[1] + bv[1]);
  o.y = pack2(d2 * rstd * gv[2] + bv[2], d3 * rstd * gv[3] + bv[3]);
  *(uint2*)(hp + lane * 4) = o;
}

// ---------------- 16B vector copy ----------------
__global__ __launch_bounds__(256) void copy16_kernel(
    uint4* __restrict__ dst, const uint4* __restrict__ src, size_t n16)
{
  size_t i = (size_t)blockIdx.x * 256 + threadIdx.x;
  if (i < n16) dst[i] = src[i];
}

// ---------------- final FC ----------------
__global__ __launch_bounds__(64) void final_fc_kernel(
    const bf16* __restrict__ h, const bf16* __restrict__ fcw,
    const bf16* __restrict__ fcb, void* __restrict__ out, int L,
    const int* __restrict__ flag)
{
  int b = blockIdx.x;
  int p = threadIdx.x;
  if (p >= PRED_) return;
  const bf16* hr = h + ((size_t)b * L + (L - 1)) * D_;
  float s = b2f(fcb[p]);
  for (int d = 0; d < D_; ++d) s += b2f(hr[d]) * b2f(fcw[d * PRED_ + p]);
  if (flag[0]) ((float*)out)[b * PRED_ + p] = s;
  else         ((bf16*)out)[b * PRED_ + p]  = f2b(s);
}

// ---------------- host ----------------
extern "C" void kernel_launch(void* const* d_in, const int* in_sizes, int n_in,
                              void* d_out, int out_size, void* d_ws, size_t ws_size,
                              hipStream_t stream)
{
  const size_t hsz = (size_t)B_ * L0_ * D_;
  char* wsc = (char*)d_ws;
  bf16* h  = (bf16*)wsc;
  bf16* Qh = (bf16*)(wsc + hsz * 2);
  bf16* Kh = (bf16*)(wsc + hsz * 4);
  bf16* Vh = (bf16*)(wsc + hsz * 6);
  char* misc = wsc + hsz * 8;
  float* Mbuf    = (float*)misc;
  float* ctx_top = Mbuf + (size_t)B_ * H_ * L0_;
  float* vmean   = ctx_top + (size_t)B_ * H_ * UMAX_ * DK_;
  int*   topbuf  = (int*)(vmean + B_ * H_ * DK_);
  int*   flag    = topbuf + B_ * H_ * UMAX_;
  float* part_m  = (float*)(flag + 4);
  float* part_s  = part_m + (size_t)NS_ * B_ * H_ * UMAX_;
  float* part_acc= part_s + (size_t)NS_ * B_ * H_ * UMAX_;
  float* vpart   = part_acc + (size_t)NS_ * B_ * H_ * UMAX_ * 128;
  bf16*  zbuf    = (bf16*)(vpart + (size_t)B_ * H_ * NSV_ * 32);
  bf16*  canon   = zbuf + 32;

  bf16* qkvT = canon;                       // 3 layers x [768][256]
  bf16* owT  = qkvT + 3 * 196608;
  bf16* f1wT = owT  + 3 * 65536;
  bf16* f2wT = f1wT + 3 * 262144;
  bf16* cwT  = f2wT + 3 * 262144;
  bf16* smallc = cwT + 2 * 196608;

  bf16* ctxb = Vh;
  bf16* ab   = Qh;
  bf16* t1   = Kh;
  bf16* hnext = Kh;

  detect_mode_kernel<<<1, 256, 0, stream>>>((const unsigned short*)d_in[0], flag, zbuf);

  const int cidx[13] = {8, 10, 12, 14, 16, 18, 19, 20, 21, 22, 24, 25, 26};
  bf16* cptr[27] = {};
  {
    bf16* p = smallc;
    for (int t = 0; t < 13; ++t) {
      int i = cidx[t];
      int n = in_sizes[i];
      cptr[i] = p;
      canon_kernel<<<(n + 255) / 256, 256, 0, stream>>>(d_in[i], p, n, flag);
      p += (n + 7) & ~7;
    }
  }
  transpose_w_kernel<<<dim3(256, 3), 256, 0, stream>>>(d_in[7],  qkvT,          256, 256, flag, 196608);
  transpose_w_kernel<<<dim3(256, 3), 256, 0, stream>>>(d_in[9],  qkvT + 65536,  256, 256, flag, 196608);
  transpose_w_kernel<<<dim3(256, 3), 256, 0, stream>>>(d_in[11], qkvT + 131072, 256, 256, flag, 196608);
  transpose_w_kernel<<<dim3(256, 3), 256, 0, stream>>>(d_in[13], owT,  256, 256, flag, 65536);
  transpose_w_kernel<<<dim3(1024, 3), 256, 0, stream>>>(d_in[15], f1wT, 256, 1024, flag, 262144);
  transpose_w_kernel<<<dim3(1024, 3), 256, 0, stream>>>(d_in[17], f2wT, 1024, 256, flag, 262144);
  transpose_cw_kernel<<<dim3(768, 2), 256, 0, stream>>>(d_in[23], cwT, flag);

  const int* idx[3] = {(const int*)d_in[1], (const int*)d_in[2], (const int*)d_in[3]};
  int us[3] = {in_sizes[1], in_sizes[2], in_sizes[3]};

  embed_kernel<<<B_ * L0_ / 8, 256, 0, stream>>>(d_in[0], d_in[4], d_in[5], d_in[6], flag, h);

  int L = L0_;
  for (int i = 0; i < 3; ++i) {
    int tokens = B_ * L;
    int u = us[i];
    int Lsh = 31 - __builtin_clz(L);
    int rm = tokens / 128;
    mfma_gemm<0,1><<<6 * rm, 256, 0, stream>>>(
        h, qkvT + (size_t)i * 196608,
        cptr[8] + i * D_, cptr[10] + i * D_, cptr[12] + i * D_,
        Qh, tokens, 768, 256, Lsh, hsz, 6);

    prob_scores_kernel<<<B_ * H_ * (L / 256), 256, 0, stream>>>(Qh, Kh, idx[i], Mbuf, L, u);
    topk_kernel<<<B_ * H_, 256, 0, stream>>>(Mbuf, topbuf, L, u);
    topq_attn_mfma<<<dim3(B_ * H_, NS_), 256, 0, stream>>>(
        Qh, Kh, Vh, topbuf, part_m, part_s, part_acc, L, u);
    vmean_part_kernel<<<B_ * H_ * NSV_, 256, 0, stream>>>(Vh, vpart, L);
    // ctxb aliases Vh; both readers of Vh (topq_attn, vmean_part) are done.
    fill_ctx_kernel<<<tokens / 8, 256, 0, stream>>>(vpart, ctxb, Lsh, L);
    attn_combine_kernel<<<B_ * H_, 256, 0, stream>>>(
        part_m, part_s, part_acc, topbuf, ctxb, L, u);
    mfma_gemm<0,0><<<2 * rm, 256, 0, stream>>>(
        ctxb, owT + (size_t)i * 65536, cptr[14] + i * D_, nullptr, nullptr,
        ab, tokens, 256, 256, 0, 0, 2);

    add_ln_kernel<<<tokens / 4, 256, 0, stream>>>(h, ab, cptr[19] + i * D_, cptr[20] + i * D_);

    const int CH = 16384;
    for (int c0 = 0; c0 < tokens; c0 += CH) {
      int cm = (tokens - c0 < CH) ? (tokens - c0) : CH;
      int rmc = cm / 128;
      mfma_gemm<1,0><<<8 * rmc, 256, 0, stream>>>(
          h + (size_t)c0 * D_, f1wT + (size_t)i * 262144, cptr[16] + i * FF_,
          nullptr, nullptr, t1, cm, FF_, 256, 0, 0, 8);
      mfma_gemm<0,0><<<2 * rmc, 256, 0, stream>>>(
          t1, f2wT + (size_t)i * 262144, cptr[18] + i * D_, nullptr, nullptr,
          ab + (size_t)c0 * D_, cm, 256, FF_, 0, 0, 2);
    }
    add_ln_kernel<<<tokens / 4, 256, 0, stream>>>(h, ab, cptr[21] + i * D_, cptr[22] + i * D_);

    if (i < 2) {
      int Lh = L / 2;
      mfma_conv_distill<<<2 * (B_ * (L / 128)), 256, 0, stream>>>(
          h, cwT + (size_t)i * 196608, cptr[24] + i * D_, hnext, zbuf, L);
      size_t n16 = (size_t)B_ * Lh * D_ / 8;
      copy16_kernel<<<(unsigned)((n16 + 255) / 256), 256, 0, stream>>>(
          (uint4*)h, (const uint4*)hnext, n16);
      L = Lh;
    }
  }
  final_fc_kernel<<<B_, 64, 0, stream>>>(h, cptr[25], cptr[26], d_out, L, flag);
}